// Round 14
// baseline (107.650 us; speedup 1.0000x reference)
//
#include <hip/hip_runtime.h>

#define C 128
#define H 128
#define W 128
#define HW (H*W)

// K1: corr partials for 25 dilated taps + g partial.
// block = (b, tile t, parity, kpair, ch-half): processes 2 same-parity output
// rows r = rbase, rbase+2 -> tap rows overlap across rows (L1 line reuse).
// 640 thr = 10 waves = (tap-row ti 0..4) x (32-ch quarter q); s = 16-ch subgroup.
__global__ __launch_bounds__(640, 6) void corr_kernel(
    const float* __restrict__ feat, const float* __restrict__ wc,
    float* __restrict__ corrG, float* __restrict__ gG)
{
    __shared__ float corr_s[2][25][W];   // [q][tap][col]
    __shared__ float g_s[2][W];          // [q][col]

    const int blk0 = blockIdx.x;
    const int blk  = (blk0 & 7) * 64 + (blk0 >> 3);  // XCD swizzle (512 = 8*64)
    const int half = blk & 1;            // 64-ch half
    const int kp   = (blk >> 1) & 1;     // k-pair
    const int par  = (blk >> 2) & 1;     // row parity
    const int t    = (blk >> 3) & 15;    // 8-row tile
    const int b    = blk >> 7;           // batch
    const int rb   = 8 * t + par + 4 * kp;   // first of 2 same-parity rows

    const int tid  = threadIdx.x;
    const int wv   = tid >> 6;           // 0..9
    const int ti   = wv >> 1;            // tap-row index 0..4
    const int q    = wv & 1;             // 32-ch quarter within the half
    const int lane = tid & 63;
    const int s    = lane >> 5;          // 16-ch subgroup
    const int pg   = lane & 31;
    const int w0   = pg * 4;             // lane owns cols w0..w0+3

    // window slots: floats [w0-4, w0+8) as 3 aligned float4; a clamped slot is
    // provably fully-OOB for this lane -> its taps are masked below.
    int sb[3];
#pragma unroll
    for (int u = 0; u < 3; ++u) {
        const int cs = w0 - 4 + 4 * u;
        sb[u] = cs < 0 ? 0 : (cs > W - 4 ? W - 4 : cs);
    }
    const int cbase = half * 64 + q * 32 + s * 16;
    const bool isCtr = (ti == 2);

#pragma unroll 1
    for (int kk = 0; kk < 2; ++kk) {
        const int  r   = rb + 2 * kk;        // output row of this pass
        const int  rt  = r - 4 + 2 * ti;     // wave's tap row
        const bool rok = (unsigned)rt < (unsigned)H;

        float acc[5][4];
        float ga[4] = {0.f, 0.f, 0.f, 0.f};
#pragma unroll
        for (int j = 0; j < 5; ++j)
#pragma unroll
            for (int p = 0; p < 4; ++p) acc[j][p] = 0.f;

        if (rok) {                           // wave-uniform
            const float* tp = feat + ((size_t)(b * C + cbase) * H + rt) * W;
            const float* cp = feat + ((size_t)(b * C + cbase) * H + r ) * W + w0;
#pragma unroll 2
            for (int c = 0; c < 16; ++c) {
                const float4 A  = *(const float4*)(tp + sb[0]);
                const float4 Bv = *(const float4*)(tp + sb[1]);
                const float4 Cv = *(const float4*)(tp + sb[2]);
                float4 D;
                if (isCtr) D = Bv;           // tap row == center row, sb[1]==w0
                else       D = *(const float4*)cp;
                const float wcv = wc[cbase + c];
                const float win[12] = {A.x, A.y, A.z, A.w,
                                       Bv.x, Bv.y, Bv.z, Bv.w,
                                       Cv.x, Cv.y, Cv.z, Cv.w};
                const float ctr[4] = {D.x, D.y, D.z, D.w};
                if (isCtr) {
#pragma unroll
                    for (int p = 0; p < 4; ++p)
                        ga[p] = fmaf(wcv, win[4 + p], ga[p]);
                }
#pragma unroll
                for (int j = 0; j < 5; ++j)
#pragma unroll
                    for (int p = 0; p < 4; ++p)
                        acc[j][p] = fmaf(ctr[p], win[p + 2 * j], acc[j][p]);
                tp += HW; cp += HW;
            }
        }

        // combine the two 16-ch subgroups within the wave
#pragma unroll
        for (int j = 0; j < 5; ++j)
#pragma unroll
            for (int p = 0; p < 4; ++p)
                acc[j][p] += __shfl_xor(acc[j][p], 32);
        if (isCtr) {
#pragma unroll
            for (int p = 0; p < 4; ++p) ga[p] += __shfl_xor(ga[p], 32);
        }

        // disjoint LDS writes (s==0 lanes cover all 128 cols); mask -> zero-pad
        if (s == 0) {
#pragma unroll
            for (int j = 0; j < 5; ++j)
#pragma unroll
                for (int p = 0; p < 4; ++p) {
                    const int  col = w0 + p - 4 + 2 * j;
                    const bool ok  = rok && ((unsigned)col < (unsigned)W);
                    corr_s[q][ti * 5 + j][w0 + p] = ok ? acc[j][p] : 0.f;
                }
            if (isCtr) {
#pragma unroll
                for (int p = 0; p < 4; ++p) g_s[q][w0 + p] = ga[p];
            }
        }
        __syncthreads();

        // store combined partials (coalesced)
        float* cg = corrG + (size_t)((b * H + r) * 2 + half) * (25 * W);
        const float* s0 = &corr_s[0][0][0];
        const float* s1 = &corr_s[1][0][0];
        for (int idx = tid; idx < 25 * W; idx += 640)
            cg[idx] = s0[idx] + s1[idx];
        if (tid < W)
            gG[(size_t)((b * H + r) * 2 + half) * W + tid] = g_s[0][tid] + g_s[1][tid];
        __syncthreads();                     // protect corr_s before next kk
    }
}

// K2: relu -> softmax over 25 taps -> sum attn*g -> + bias.
__global__ __launch_bounds__(128) void soft_kernel(
    const float* __restrict__ corrG, const float* __restrict__ gG,
    const float* __restrict__ bc, float* __restrict__ out)
{
    const int blk0 = blockIdx.x;
    const int xcd  = blk0 & 7;
    const int idx  = blk0 >> 3;
    const int b    = xcd >> 1;
    const int r    = (xcd & 1) * 64 + idx;
    const int w    = threadIdx.x;

    const size_t base = ((size_t)(b * H + r)) * 2;
    const float* c0 = corrG + base * (25 * W);
    const float* c1 = c0 + (25 * W);

    float v[25], m = 0.f;
#pragma unroll
    for (int n = 0; n < 25; ++n) {
        v[n] = fmaxf(c0[n * W + w] + c1[n * W + w], 0.f);
        m = fmaxf(m, v[n]);
    }
    float sum = 0.f, num = 0.f;
#pragma unroll
    for (int i = 0; i < 5; ++i) {
        const int  rt  = r - 4 + 2 * i;
        const bool riv = (unsigned)rt < (unsigned)H;
        const size_t gb = ((size_t)(b * H + (riv ? rt : 0))) * 2 * W;
#pragma unroll
        for (int j = 0; j < 5; ++j) {
            const float e = __expf(v[i * 5 + j] - m);
            sum += e;
            const int  wt = w - 4 + 2 * j;
            const bool ok = riv && ((unsigned)wt < (unsigned)W);
            const int  wi = ok ? wt : 0;
            const float gv = gG[gb + wi] + gG[gb + W + wi];
            num = fmaf(e, ok ? gv : 0.f, num);
        }
    }
    out[((size_t)(b * H + r)) * W + w] = num / sum + bc[0];
}

extern "C" void kernel_launch(void* const* d_in, const int* in_sizes, int n_in,
                              void* d_out, int out_size, void* d_ws, size_t ws_size,
                              hipStream_t stream) {
    const float* feat = (const float*)d_in[0];
    const float* wcls = (const float*)d_in[1];
    const float* bcls = (const float*)d_in[2];
    float* outp  = (float*)d_out;
    float* corrG = (float*)d_ws;                       // 1024*3200*4 = 13.1 MB
    float* gG    = corrG + (size_t)1024 * 25 * W;      // 1024*128*4  = 0.5 MB

    corr_kernel<<<dim3(512), dim3(640), 0, stream>>>(feat, wcls, corrG, gG);
    soft_kernel<<<dim3(512), dim3(128), 0, stream>>>(corrG, gG, bcls, outp);
}